// Round 4
// baseline (93.413 us; speedup 1.0000x reference)
//
#include <hip/hip_runtime.h>

// Sentence_Rep: masked mean over sequence axis.
//   in : float32 [B=2048, S=200, D=300]
//   out: float32 [B, D] = sum_s(v[b,s,:]) / count_s(any(v[b,s,:] != 0))
//   (masked rows are all-zero, so unconditional sum == masked sum; only the
//    count needs the mask.)
//
// This version makes the read stream memcpy-shaped: each sentence is read as
// a flat array of 15000 float4 with block-stride 256 -> every load is a
// full-wave, 128B-aligned dense dwordx4 (no partial-lane tail loads, no
// line-splitting). A float4 never straddles a row (1200 % 16 == 0), so slot
// f maps to row f/75, dimslot f%75. Per-dim sums accumulate in per-wave LDS
// buffers (read-add-write; 64 consecutive f%75 within a wave are distinct ->
// race-free, ~2-way bank aliasing = free). Row mask = per-thread 200-bit
// register bitmask, OR-reduced once at the end.

typedef float f4 __attribute__((ext_vector_type(4)));

#define SR_BATCH     2048
#define SR_SEQ       200
#define SR_DIM       300
#define F4_PER_ROW   75                      // 300 / 4
#define F4_PER_SENT  (SR_SEQ * F4_PER_ROW)   // 15000
#define NTHREADS     256
#define NSWEEP_FULL  58                      // 58*256 = 14848
#define TAIL_THREADS 152                     // 15000 - 14848

__global__ __launch_bounds__(256) void sentence_rep_kernel(
    const float* __restrict__ in, float* __restrict__ out) {
    const int b    = blockIdx.x;
    const int t    = threadIdx.x;
    const int wave = t >> 6;
    const int lane = t & 63;

    __shared__ f4 s_acc[4][F4_PER_ROW];          // per-wave dim accumulators
    __shared__ unsigned long long s_mask[4][4];  // per-wave OR'd row masks
    __shared__ float s_count;

    // Zero-init accumulators (300 f4 slots, 256 threads).
    {
        f4* flat = &s_acc[0][0];
        f4 z = {0.f, 0.f, 0.f, 0.f};
        flat[t] = z;
        if (t < 4 * F4_PER_ROW - NTHREADS) flat[NTHREADS + t] = z;
    }
    __syncthreads();

    const f4* __restrict__ src = (const f4*)(in + (size_t)b * (SR_SEQ * SR_DIM));
    f4* myacc = &s_acc[wave][0];

    // Per-thread 200-bit row-nonzero mask.
    unsigned long long m0 = 0, m1 = 0, m2 = 0, m3 = 0;

    int f = t;
    #pragma unroll 2
    for (int k = 0; k < NSWEEP_FULL; ++k, f += NTHREADS) {
        f4 v = src[f];
        const int r = f / F4_PER_ROW;            // row (magic-mul)
        const int c = f - r * F4_PER_ROW;        // dimslot

        f4 a = myacc[c];
        a.x += v.x; a.y += v.y; a.z += v.z; a.w += v.w;
        myacc[c] = a;

        const bool nz = (v.x != 0.f) | (v.y != 0.f) | (v.z != 0.f) | (v.w != 0.f);
        const unsigned long long bit = nz ? (1ULL << (r & 63)) : 0ULL;
        const int sel = r >> 6;
        m0 |= (sel == 0) ? bit : 0ULL;
        m1 |= (sel == 1) ? bit : 0ULL;
        m2 |= (sel == 2) ? bit : 0ULL;
        m3 |= (sel == 3) ? bit : 0ULL;
    }
    // Tail sweep: slots 14848..14999 (threads 0..151).
    if (t < TAIL_THREADS) {
        f4 v = src[f];
        const int r = f / F4_PER_ROW;
        const int c = f - r * F4_PER_ROW;

        f4 a = myacc[c];
        a.x += v.x; a.y += v.y; a.z += v.z; a.w += v.w;
        myacc[c] = a;

        const bool nz = (v.x != 0.f) | (v.y != 0.f) | (v.z != 0.f) | (v.w != 0.f);
        const unsigned long long bit = nz ? (1ULL << (r & 63)) : 0ULL;
        const int sel = r >> 6;
        m0 |= (sel == 0) ? bit : 0ULL;
        m1 |= (sel == 1) ? bit : 0ULL;
        m2 |= (sel == 2) ? bit : 0ULL;
        m3 |= (sel == 3) ? bit : 0ULL;
    }

    // OR-reduce the 4 mask words across the wave (once, out of the hot loop).
    for (int off = 1; off < 64; off <<= 1) {
        m0 |= __shfl_xor(m0, off, 64);
        m1 |= __shfl_xor(m1, off, 64);
        m2 |= __shfl_xor(m2, off, 64);
        m3 |= __shfl_xor(m3, off, 64);
    }
    if (lane == 0) {
        s_mask[wave][0] = m0; s_mask[wave][1] = m1;
        s_mask[wave][2] = m2; s_mask[wave][3] = m3;
    }
    __syncthreads();

    if (t == 0) {
        unsigned long long r0 = s_mask[0][0] | s_mask[1][0] | s_mask[2][0] | s_mask[3][0];
        unsigned long long r1 = s_mask[0][1] | s_mask[1][1] | s_mask[2][1] | s_mask[3][1];
        unsigned long long r2 = s_mask[0][2] | s_mask[1][2] | s_mask[2][2] | s_mask[3][2];
        unsigned long long r3 = s_mask[0][3] | s_mask[1][3] | s_mask[2][3] | s_mask[3][3];
        s_count = (float)(__popcll(r0) + __popcll(r1) + __popcll(r2) + __popcll(r3));
    }
    __syncthreads();

    // Final: sum 4 wave-buffers per dimslot, divide by count, store f4.
    if (t < F4_PER_ROW) {
        const float total = s_count;
        f4 o0 = s_acc[0][t], o1 = s_acc[1][t], o2 = s_acc[2][t], o3 = s_acc[3][t];
        f4 o;
        o.x = (o0.x + o1.x + o2.x + o3.x) / total;
        o.y = (o0.y + o1.y + o2.y + o3.y) / total;
        o.z = (o0.z + o1.z + o2.z + o3.z) / total;
        o.w = (o0.w + o1.w + o2.w + o3.w) / total;
        ((f4*)(out + (size_t)b * SR_DIM))[t] = o;
    }
}

extern "C" void kernel_launch(void* const* d_in, const int* in_sizes, int n_in,
                              void* d_out, int out_size, void* d_ws, size_t ws_size,
                              hipStream_t stream) {
    const float* in = (const float*)d_in[0];
    float* out = (float*)d_out;
    sentence_rep_kernel<<<SR_BATCH, NTHREADS, 0, stream>>>(in, out);
}

// Round 5
// 76.583 us; speedup vs baseline: 1.2198x; 1.2198x over previous
//
#include <hip/hip_runtime.h>

// Sentence_Rep: masked mean over sequence axis.
//   in : float32 [B=2048, S=200, D=300]
//   out: float32 [B, D] = sum_s(v[b,s,:]) / count_s(any(v[b,s,:] != 0))
//   (masked rows are all-zero, so unconditional sum == masked sum; only the
//    count needs the mask.)
//
// R5: R3 structure (register accumulators, bitmask count, no in-loop
// cross-lane ops) + NON-TEMPORAL loads. The 491.5 MB input exceeds the
// 256 MB L3 and is cyclically re-read (graph replay) -> ~0% hit rate but
// full insertion/eviction overhead on every line. nt loads skip insertion.

typedef float f4 __attribute__((ext_vector_type(4)));

#define SR_BATCH 2048
#define SR_SEQ   200
#define SR_DIM   300   // = 75 float4

__global__ __launch_bounds__(256) void sentence_rep_kernel(
    const float* __restrict__ in, float* __restrict__ out) {
    const int b    = blockIdx.x;
    const int lane = threadIdx.x & 63;
    const int wave = threadIdx.x >> 6;   // 0..3

    const float* base = in + (size_t)b * (SR_SEQ * SR_DIM);

    // Per-lane register accumulators:
    //   acc0 -> dims [4*lane, 4*lane+3]           (lanes 0..63, floats 0..255)
    //   acc1 -> dims [256+4*lane, 256+4*lane+3]   (lanes 0..10, floats 256..299)
    float a0x = 0.f, a0y = 0.f, a0z = 0.f, a0w = 0.f;
    float a1x = 0.f, a1y = 0.f, a1z = 0.f, a1w = 0.f;

    const bool has_tail = (lane < 11);   // 64 + 11 = 75 float4 = 300 floats

    // Each wave owns rows {wave, wave+4, ..., wave+196}: 50 iterations.
    // Per-lane bitmask: bit i = "lane saw a nonzero in its slice of row i".
    unsigned long long rowbits = 0ULL;

    int iter = 0;
    for (int s = wave; s < SR_SEQ; s += 4, ++iter) {
        const f4* row4 = (const f4*)(base + s * SR_DIM);
        f4 v0 = __builtin_nontemporal_load(&row4[lane]);
        f4 v1 = {0.f, 0.f, 0.f, 0.f};
        if (has_tail) v1 = __builtin_nontemporal_load(&row4[64 + lane]);

        bool nz = (v0.x != 0.f) | (v0.y != 0.f) | (v0.z != 0.f) | (v0.w != 0.f) |
                  (v1.x != 0.f) | (v1.y != 0.f) | (v1.z != 0.f) | (v1.w != 0.f);
        rowbits |= ((unsigned long long)nz) << iter;

        // Unconditional accumulate: all-zero rows contribute exactly 0.
        a0x += v0.x; a0y += v0.y; a0z += v0.z; a0w += v0.w;
        a1x += v1.x; a1y += v1.y; a1z += v1.z; a1w += v1.w;
    }

    // OR-reduce rowbits across the 64 lanes (out of the hot loop).
    for (int off = 1; off < 64; off <<= 1)
        rowbits |= __shfl_xor(rowbits, off, 64);
    const float cnt = (float)__popcll(rowbits);   // kept rows among this wave's 50

    // Cross-wave reduction through LDS.
    __shared__ float s_acc[4][304];      // 4 waves x 300 dims (pad to 304)
    __shared__ float s_cnt[4];

    {
        float* dst = &s_acc[wave][0];
        const int d0 = lane * 4;
        dst[d0 + 0] = a0x; dst[d0 + 1] = a0y; dst[d0 + 2] = a0z; dst[d0 + 3] = a0w;
        if (has_tail) {
            const int d1 = 256 + lane * 4;
            dst[d1 + 0] = a1x; dst[d1 + 1] = a1y; dst[d1 + 2] = a1z; dst[d1 + 3] = a1w;
        }
        if (lane == 0) s_cnt[wave] = cnt;
    }
    __syncthreads();

    const float total = s_cnt[0] + s_cnt[1] + s_cnt[2] + s_cnt[3];
    float* orow = out + (size_t)b * SR_DIM;
    for (int d = threadIdx.x; d < SR_DIM; d += 256) {
        float sum = s_acc[0][d] + s_acc[1][d] + s_acc[2][d] + s_acc[3][d];
        orow[d] = sum / total;
    }
}

extern "C" void kernel_launch(void* const* d_in, const int* in_sizes, int n_in,
                              void* d_out, int out_size, void* d_ws, size_t ws_size,
                              hipStream_t stream) {
    const float* in = (const float*)d_in[0];
    float* out = (float*)d_out;
    sentence_rep_kernel<<<SR_BATCH, 256, 0, stream>>>(in, out);
}